// Round 2
// baseline (1763.490 us; speedup 1.0000x reference)
//
#include <hip/hip_runtime.h>
#include <math.h>

#define T_    256
#define D_    1024
#define C_    512
#define H_    4
#define DH_   128
#define BNB   160
#define LEPS  1e-5f
#define INV_E 0.36787944117144233f
#define SCALE_ 0.08838834764831845f   // 1/sqrt(128)
#define LDT   40                      // padded LDS stride (attn/head kernels)
#define XROW  264192                  // padded x row block: 258*1024 elems per bn

typedef unsigned short ushort;
typedef unsigned int   uint;
typedef __attribute__((ext_vector_type(8))) short short8;   // 8 bf16 (4 VGPRs)
typedef __attribute__((ext_vector_type(4))) float f32x4;

__device__ __forceinline__ ushort f2b(float f) {            // fp32 -> bf16 RNE
    uint u = __float_as_uint(f);
    u += 0x7fffu + ((u >> 16) & 1u);
    return (ushort)(u >> 16);
}
__device__ __forceinline__ float b2f(ushort u) {
    return __uint_as_float(((uint)u) << 16);
}
__device__ __forceinline__ uint pk(float a, float b) {
    return (uint)f2b(a) | ((uint)f2b(b) << 16);
}
// async global->LDS DMA, 16B/lane; lds dest is wave-uniform base (+lane*16 by HW)
__device__ __forceinline__ void gl2lds(const void* g, void* l) {
    __builtin_amdgcn_global_load_lds(
        (const __attribute__((address_space(1))) void*)g,
        (__attribute__((address_space(3))) void*)l, 16, 0, 0);
}

// ---------------------------------------------------------------- zero fill
__global__ void zero_k(float* __restrict__ p, int n) {
    int i = blockIdx.x * 256 + threadIdx.x;
    if (i < n) p[i] = 0.0f;
}

// ---------------- x fp32 -> bf16 into padded layout [bn][258][1024], data at row t+1
__global__ void xcvt_k(const float* __restrict__ src, ushort* __restrict__ dst, int n4) {
    int i = blockIdx.x * 256 + threadIdx.x;
    if (i < n4) {
        float4 f = ((const float4*)src)[i];
        uint2 v;
        v.x = pk(f.x, f.y);
        v.y = pk(f.z, f.w);
        int e   = i * 4;
        int bn  = e >> 18;            // 262144 elems per bn
        int rem = e & 262143;
        ((uint2*)(dst + (size_t)bn * XROW + 1024 + rem))[0] = v;
    }
}

// ---------------- zero the pad rows (rows 0 and 257 of each bn)
__global__ void xpad_k(ushort* __restrict__ dst, int nbn) {
    int i = blockIdx.x * 256 + threadIdx.x;
    if (i >= nbn * 1024) return;
    int bn = i >> 10, j = i & 1023;
    int r = j >> 9, c = j & 511;
    uint* base = (uint*)(dst + (size_t)bn * XROW);
    base[(r ? (XROW - 1024) / 2 : 0) + c] = 0u;
}

// ---------------- tiled transpose+convert: src (K,N) fp32 -> dst (N,K) bf16
__global__ __launch_bounds__(256)
void tconv_k(const float* __restrict__ src, ushort* __restrict__ dst,
             int K, int N) {
    __shared__ float tile[32][33];
    int kb = blockIdx.x * 32, nb = blockIdx.y * 32;
    int tx = threadIdx.x & 31, ty = threadIdx.x >> 5;   // 32 x 8
#pragma unroll
    for (int i = 0; i < 32; i += 8)
        tile[ty + i][tx] = src[(size_t)(kb + ty + i) * N + nb + tx];
    __syncthreads();
#pragma unroll
    for (int i = 0; i < 32; i += 8)
        dst[(size_t)(nb + ty + i) * K + kb + tx] = f2b(tile[tx][ty + i]);
}

// ---------------- elementwise fp32 -> bf16 convert
__global__ void bcvt_k(const float* __restrict__ src, ushort* __restrict__ dst, int n) {
    int i = blockIdx.x * 256 + threadIdx.x;
    if (i < n) dst[i] = f2b(src[i]);
}

// -------- W_emb (C,1024,3) -> bf16 [C][3072] with k = dt*1024+ci ordering
__global__ void wemb_k(const float* __restrict__ W, ushort* __restrict__ Wt) {
    int idx = blockIdx.x * 256 + threadIdx.x;
    if (idx >= C_ * 3072) return;
    int c = idx / 3072, k = idx % 3072;
    int dt = k >> 10, ci = k & 1023;
    Wt[idx] = f2b(W[(size_t)c * 3072 + ci * 3 + dt]);
}

// -------------------------------- s[j] = sum_k exp(-|j-k|/e)  (a2 col sums)
__global__ void a2_colsum_k(float* __restrict__ s) {
    int j = threadIdx.x;
    float acc = 0.0f;
    for (int k = 0; k < T_; k++) acc += expf(-fabsf((float)(j - k)) * INV_E);
    s[j] = acc;
}

// -------------------------------- A2 bf16 [i][j] = exp(-|i-j|/e)/s[j]
__global__ void a2fill_k(const float* __restrict__ s, ushort* __restrict__ A2) {
    int i = blockIdx.x, j = threadIdx.x;
    A2[i * 256 + j] = f2b(expf(-fabsf((float)(i - j)) * INV_E) / s[j]);
}

// ------------------- LayerNorm: one wave per row, shuffle-only reductions
__global__ __launch_bounds__(256)
void ln_k(const ushort* __restrict__ X, const float* __restrict__ g,
          const float* __restrict__ b, ushort* __restrict__ Z) {
    int row  = blockIdx.x * 4 + (threadIdx.x >> 6);
    int lane = threadIdx.x & 63;
    const ushort* xr = X + (size_t)row * C_ + lane * 8;
    uint4 raw = *(const uint4*)xr;
    float f[8];
    f[0] = __uint_as_float(raw.x << 16); f[1] = __uint_as_float(raw.x & 0xffff0000u);
    f[2] = __uint_as_float(raw.y << 16); f[3] = __uint_as_float(raw.y & 0xffff0000u);
    f[4] = __uint_as_float(raw.z << 16); f[5] = __uint_as_float(raw.z & 0xffff0000u);
    f[6] = __uint_as_float(raw.w << 16); f[7] = __uint_as_float(raw.w & 0xffff0000u);
    float s = 0.0f, s2 = 0.0f;
#pragma unroll
    for (int u = 0; u < 8; u++) { s += f[u]; s2 += f[u] * f[u]; }
#pragma unroll
    for (int m = 1; m < 64; m <<= 1) {
        s  += __shfl_xor(s, m);
        s2 += __shfl_xor(s2, m);
    }
    float mean = s * (1.0f / C_);
    float var  = s2 * (1.0f / C_) - mean * mean;
    float rinv = rsqrtf(var + LEPS);
    const float* gp = g + lane * 8;
    const float* bp = b + lane * 8;
    float4 g0 = *(const float4*)gp, g1 = *(const float4*)(gp + 4);
    float4 b0 = *(const float4*)bp, b1 = *(const float4*)(bp + 4);
    uint4 outv;
    outv.x = pk((f[0]-mean)*rinv*g0.x+b0.x, (f[1]-mean)*rinv*g0.y+b0.y);
    outv.y = pk((f[2]-mean)*rinv*g0.z+b0.z, (f[3]-mean)*rinv*g0.w+b0.w);
    outv.z = pk((f[4]-mean)*rinv*g1.x+b1.x, (f[5]-mean)*rinv*g1.y+b1.y);
    outv.w = pk((f[6]-mean)*rinv*g1.z+b1.z, (f[7]-mean)*rinv*g1.w+b1.w);
    *(uint4*)(Z + (size_t)row * C_ + lane * 8) = outv;
}

// ======= bf16 MFMA GEMM, 256x256 tile, BK=64, deep-lookahead schedule =======
// C(MxN) = A(MxK,bf16) @ B'(NxK,bf16)  [+bias] [ACT 1=gelu 2=relu] [+R bf16]
// CONV=1: A implicit im2row of padded Xp ([bn][258][1024], zero pad rows)
//
// Per K-tile (4 phases, double-buffered LDS at tile granularity, halves
// staged/consumed independently):
//   P1: ds_read A03(t)+B23(t) | lgkm(4) | MFMA mf0-3 x nf0-1 | bar
//   P2: stage A0(t+2),B0(t+2) | lgkm(0) | MFMA mf0-3 x nf2-3 | vm(12) bar
//   P3: stage B1(t+2); ds_read A47(t) | lgkm(0) | MFMA mf4-7 x nf0-1 | vm(10) bar
//   P4: stage A1(t+2); ds_read B01(t+1) | MFMA mf4-7 x nf2-3 | vm(10) bar
// Stage->consume distance is 5-7 phases (>=3500cy >> 900cy HBM latency);
// steady waits vmcnt(12/10/10) verified by per-thread FIFO trace (prologue,
// steady state, epilogue). Region overwrite hazards: every stage targets a
// region whose ds_reads were lgkm-drained in an earlier phase + barrier.
// LDS XOR-swizzle slot16^=(row&7) both-sides (pre-swizzled source, rule 21).

#define VMW_12 asm volatile("s_waitcnt vmcnt(12)" ::: "memory")
#define VMW_10 asm volatile("s_waitcnt vmcnt(10)" ::: "memory")
#define VMW_8  asm volatile("s_waitcnt vmcnt(8)"  ::: "memory")
#define VMW_4  asm volatile("s_waitcnt vmcnt(4)"  ::: "memory")
#define VMW_2  asm volatile("s_waitcnt vmcnt(2)"  ::: "memory")
#define VMW_0  asm volatile("s_waitcnt vmcnt(0)"  ::: "memory")
#define VMW_N
#define BAR() __builtin_amdgcn_s_barrier()
#define LGK4 do { asm volatile("s_waitcnt lgkmcnt(4)" ::: "memory"); \
                  __builtin_amdgcn_sched_barrier(0); } while (0)
#define LGK0 do { asm volatile("s_waitcnt lgkmcnt(0)" ::: "memory"); \
                  __builtin_amdgcn_sched_barrier(0); } while (0)

#define TILE(kt, S, W2, W3, W4, R4) do {                                       \
    /* ---- P1: reads af03(kt)+bf23(kt); MFMA (mf0-3 x nf0-1) ---- */          \
    _Pragma("unroll") for (int mf = 0; mf < 4; mf++)                           \
      _Pragma("unroll") for (int ks = 0; ks < 2; ks++)                         \
        af[mf][ks] = ldA(kt, mf, ks);                                          \
    _Pragma("unroll") for (int nf = 2; nf < 4; nf++)                           \
      _Pragma("unroll") for (int ks = 0; ks < 2; ks++)                         \
        bf[nf][ks] = ldB(kt, nf, ks);                                          \
    LGK4;                                                                      \
    __builtin_amdgcn_s_setprio(1);                                             \
    _Pragma("unroll") for (int ks = 0; ks < 2; ks++)                           \
      _Pragma("unroll") for (int mf = 0; mf < 4; mf++)                         \
        _Pragma("unroll") for (int nf = 0; nf < 2; nf++)                       \
          acc[mf][nf] = __builtin_amdgcn_mfma_f32_16x16x32_bf16(               \
              af[mf][ks], bf[nf][ks], acc[mf][nf], 0, 0, 0);                   \
    __builtin_amdgcn_s_setprio(0);                                             \
    BAR();                                                                     \
    /* ---- P2: stage A0(kt+2),B0(kt+2); MFMA (mf0-3 x nf2-3) ---- */          \
    if (S) { stageA((kt) + 2, 0); stageB((kt) + 2, 0); }                       \
    LGK0;                                                                      \
    __builtin_amdgcn_s_setprio(1);                                             \
    _Pragma("unroll") for (int ks = 0; ks < 2; ks++)                           \
      _Pragma("unroll") for (int mf = 0; mf < 4; mf++)                         \
        _Pragma("unroll") for (int nf = 2; nf < 4; nf++)                       \
          acc[mf][nf] = __builtin_amdgcn_mfma_f32_16x16x32_bf16(               \
              af[mf][ks], bf[nf][ks], acc[mf][nf], 0, 0, 0);                   \
    __builtin_amdgcn_s_setprio(0);                                             \
    VMW_##W2; BAR();                                                           \
    /* ---- P3: stage B1(kt+2); reads af47(kt); MFMA (mf4-7 x nf0-1) ---- */   \
    if (S) stageB((kt) + 2, 1);                                                \
    _Pragma("unroll") for (int mf = 0; mf < 4; mf++)                           \
      _Pragma("unroll") for (int ks = 0; ks < 2; ks++)                         \
        af[mf][ks] = ldA(kt, mf + 4, ks);                                      \
    LGK0;                                                                      \
    __builtin_amdgcn_s_setprio(1);                                             \
    _Pragma("unroll") for (int ks = 0; ks < 2; ks++)                           \
      _Pragma("unroll") for (int mf = 0; mf < 4; mf++)                         \
        _Pragma("unroll") for (int nf = 0; nf < 2; nf++)                       \
          acc[mf + 4][nf] = __builtin_amdgcn_mfma_f32_16x16x32_bf16(           \
              af[mf][ks], bf[nf][ks], acc[mf + 4][nf], 0, 0, 0);               \
    __builtin_amdgcn_s_setprio(0);                                             \
    VMW_##W3; BAR();                                                           \
    /* ---- P4: stage A1(kt+2); pre-read bf01(kt+1); MFMA (mf4-7 x nf2-3) - */ \
    if (S) stageA((kt) + 2, 1);                                                \
    if (R4)                                                                    \
      _Pragma("unroll") for (int nf = 0; nf < 2; nf++)                         \
        _Pragma("unroll") for (int ks = 0; ks < 2; ks++)                       \
          bf[nf][ks] = ldB((kt) + 1, nf, ks);                                  \
    __builtin_amdgcn_s_setprio(1);                                             \
    _Pragma("unroll") for (int ks = 0; ks < 2; ks++)                           \
      _Pragma("unroll") for (int mf = 0; mf < 4; mf++)                         \
        _Pragma("unroll") for (int nf = 2; nf < 4; nf++)                       \
          acc[mf + 4][nf] = __builtin_amdgcn_mfma_f32_16x16x32_bf16(           \
              af[mf][ks], bf[nf][ks], acc[mf + 4][nf], 0, 0, 0);               \
    __builtin_amdgcn_s_setprio(0);                                             \
    VMW_##W4; BAR();                                                           \
} while (0)

template<int CONV, int ACT, int RESID, int OUTBF>
__global__ __launch_bounds__(512, 2)
void gemm256_k(const ushort* __restrict__ A, const ushort* __restrict__ B,
               const float* __restrict__ bias, const ushort* __restrict__ R,
               void* __restrict__ Cout, int M, int N, int K,
               const ushort* __restrict__ Xp) {
    // LDS: [buf(2)][half(2)][128 rows][64 cols] bf16 for A and B  (128 KiB)
    __shared__ __align__(16) ushort As[32768];
    __shared__ __align__(16) ushort Bs[32768];
    const int tid  = threadIdx.x;
    const int wave = tid >> 6, lane = tid & 63;
    const int wm = wave >> 2, wn = wave & 3;        // 2 x 4 wave grid
    const int lm = lane & 15, quad = lane >> 4;

    // ---- XCD-aware swizzle: all N-panels of one M-tile on one XCD ----
    const int NP = gridDim.x, My = gridDim.y;
    int m_idx, n_idx;
    if ((My & 7) == 0) {
        int bid = blockIdx.y * NP + blockIdx.x;
        m_idx = (bid & 7) + 8 * (bid / (8 * NP));
        n_idx = (bid >> 3) % NP;
    } else {
        m_idx = blockIdx.y; n_idx = blockIdx.x;
    }
    const int m0 = m_idx * 256, n0 = n_idx * 256;

    // staging lane geometry: 8 lanes per row, pre-swizzled source column
    const int srow = lane >> 3;                 // row-in-8 (== tile row mod 8)
    const int scol = ((lane & 7) ^ srow) << 3;  // swizzled source elem offset

    auto stageA = [&](int kt, int half) {
        ushort* lds = As + (((kt & 1) * 2 + half) << 13) + (wave << 9);
        int r0 = half * 128 + wave * 8 + srow;
        if (CONV) {
            int k0 = kt << 6;
            int dt = k0 >> 10;
            int cb = (k0 & 1023) + scol;
            int g0 = m0 + r0;
            gl2lds(Xp + (size_t)(g0 >> 8) * XROW + ((g0 & 255) + dt) * 1024 + cb, lds);
            int g1 = g0 + 64;
            gl2lds(Xp + (size_t)(g1 >> 8) * XROW + ((g1 & 255) + dt) * 1024 + cb, lds + 4096);
        } else {
            const ushort* ga = A + (size_t)(m0 + r0) * K + (kt << 6) + scol;
            gl2lds(ga, lds);
            gl2lds(ga + (size_t)64 * K, lds + 4096);
        }
    };
    auto stageB = [&](int kt, int half) {
        ushort* lds = Bs + (((kt & 1) * 2 + half) << 13) + (wave << 9);
        const ushort* gb = B + (size_t)(n0 + half * 128 + wave * 8 + srow) * K
                             + (kt << 6) + scol;
        gl2lds(gb, lds);
        gl2lds(gb + (size_t)64 * K, lds + 4096);
    };

    // fragment loads (swizzled ds_read, matches staged layout)
    auto ldA = [&](int kt, int mf, int ks) -> short8 {
        int r = wm * 16 + mf * 32 + lm;             // tile row (mf interleaved)
        int slot = (quad + ks * 4) ^ (lm & 7);
        return *(const short8*)&As[(((kt & 1) * 2 + (r >> 7)) << 13)
                                   + (r & 127) * 64 + slot * 8];
    };
    auto ldB = [&](int kt, int nf, int ks) -> short8 {
        int r = wn * 16 + nf * 64 + lm;             // tile col (nf interleaved)
        int slot = (quad + ks * 4) ^ (lm & 7);
        return *(const short8*)&Bs[(((kt & 1) * 2 + (r >> 7)) << 13)
                                   + (r & 127) * 64 + slot * 8];
    };

    short8 af[4][2], bf[4][2];
    f32x4 acc[8][4];
#pragma unroll
    for (int mf = 0; mf < 8; mf++)
#pragma unroll
        for (int nf = 0; nf < 4; nf++) acc[mf][nf] = (f32x4){0.f, 0.f, 0.f, 0.f};

    const int NT = K >> 6;
    // prologue: stage tiles 0,1 in FIFO order matching steady state:
    //   A0(0),B0(0),B1(0),A1(0),A0(1),B0(1),B1(1),A1(1)
    stageA(0, 0); stageB(0, 0); stageB(0, 1); stageA(0, 1);
    stageA(1, 0); stageB(1, 0); stageB(1, 1); stageA(1, 1);
    VMW_10;          // 16 loads out; drain 6: A0(0),B0(0),B1(0) landed
    BAR();
    // pre-issue bf01(0) reads (steady state: issued by previous tile's P4)
#pragma unroll
    for (int nf = 0; nf < 2; nf++)
#pragma unroll
        for (int ks = 0; ks < 2; ks++) bf[nf][ks] = ldB(0, nf, ks);

    for (int kt = 0; kt < NT - 2; kt++)
        TILE(kt, 1, 12, 10, 10, 1);
    TILE(NT - 2, 0, 8, 4, 2, 1);
    TILE(NT - 1, 0, 0, N, N, 0);

    // ---- epilogue ----
#pragma unroll
    for (int mf = 0; mf < 8; mf++) {
        int grow0 = m0 + wm * 16 + mf * 32 + quad * 4;
#pragma unroll
        for (int nf = 0; nf < 4; nf++) {
            int gcol = n0 + wn * 16 + nf * 64 + lm;
            float bia = bias ? bias[gcol] : 0.0f;
            f32x4 v = acc[mf][nf];
#pragma unroll
            for (int i = 0; i < 4; i++) {
                int grow = grow0 + i;
                float val = v[i] + bia;
                if (ACT == 1) val = val * 0.5f * (1.0f + erff(val * 0.70710678118654752f));
                if (ACT == 2) val = fmaxf(val, 0.0f);
                if (RESID) val += b2f(R[(size_t)grow * N + gcol]);
                if (OUTBF) ((ushort*)Cout)[(size_t)grow * N + gcol] = f2b(val);
                else       ((float*)Cout)[(size_t)grow * N + gcol]  = val;
            }
        }
    }
}

// ============== bf16 MFMA GEMM, 128x128 tile, BK=32 (R0-proven path) ========
template<int CONV, int ACT, int RESID, int OUTBF>
__global__ __launch_bounds__(256)
void gemm_k(const ushort* __restrict__ A, const ushort* __restrict__ B,
            const float* __restrict__ bias, const ushort* __restrict__ R,
            void* __restrict__ Cout, int M, int N, int K,
            const ushort* __restrict__ Xp) {
    __shared__ __align__(16) ushort As[128 * 32];
    __shared__ __align__(16) ushort Bs[128 * 32];
    const int tid  = threadIdx.x;
    const int lane = tid & 63, wave = tid >> 6;
    const int wr = wave >> 1, wc = wave & 1;
    const int lm = lane & 15, quad = lane >> 4;

    const int NP = gridDim.x, My = gridDim.y;
    int m_idx, n_idx;
    if ((My & 7) == 0) {
        int bid = blockIdx.y * NP + blockIdx.x;
        m_idx = (bid & 7) + 8 * (bid / (8 * NP));
        n_idx = (bid >> 3) % NP;
    } else {
        m_idx = blockIdx.y; n_idx = blockIdx.x;
    }
    const int m0 = m_idx * 128, n0 = n_idx * 128;

    const int srow   = lane >> 2;        // 0..15
    const int schunk = (lane & 3) * 8;   // k offset (elems)
    ushort* AsW = As + wave * 32 * 32;
    ushort* BsW = Bs + wave * 32 * 32;

    f32x4 acc[4][4];
#pragma unroll
    for (int mt = 0; mt < 4; mt++)
#pragma unroll
        for (int nt = 0; nt < 4; nt++) acc[mt][nt] = (f32x4){0.f, 0.f, 0.f, 0.f};

    for (int k0 = 0; k0 < K; k0 += 32) {
        if (CONV) {
            int dt = k0 >> 10;
            int ci = (k0 & 1023) + schunk;
            int g0 = m0 + wave * 32 + srow;
            int bn0 = g0 >> 8, t0 = g0 & 255;
            int g1 = g0 + 16;
            int bn1 = g1 >> 8, t1 = g1 & 255;
            gl2lds(Xp + (size_t)bn0 * XROW + (t0 + dt) * 1024 + ci, AsW);
            gl2lds(Xp + (size_t)bn1 * XROW + (t1 + dt) * 1024 + ci, AsW + 16 * 32);
        } else {
            const ushort* ga = A + (size_t)(m0 + wave * 32 + srow) * K + k0 + schunk;
            gl2lds(ga, AsW);
            gl2lds(ga + (size_t)16 * K, AsW + 16 * 32);
        }
        {
            const ushort* gb = B + (size_t)(n0 + wave * 32 + srow) * K + k0 + schunk;
            gl2lds(gb, BsW);
            gl2lds(gb + (size_t)16 * K, BsW + 16 * 32);
        }
        __syncthreads();
        short8 af[4], bfv[4];
#pragma unroll
        for (int mt = 0; mt < 4; mt++)
            af[mt] = *(const short8*)&As[(wr * 64 + mt * 16 + lm) * 32 + quad * 8];
#pragma unroll
        for (int nt = 0; nt < 4; nt++)
            bfv[nt] = *(const short8*)&Bs[(wc * 64 + nt * 16 + lm) * 32 + quad * 8];
#pragma unroll
        for (int mt = 0; mt < 4; mt++)
#pragma unroll
            for (int nt = 0; nt < 4; nt++)
                acc[mt][nt] = __builtin_amdgcn_mfma_f32_16x16x32_bf16(
                    af[mt], bfv[nt], acc[mt][nt], 0, 0, 0);
        __syncthreads();
    }

#pragma unroll
    for (int mt = 0; mt < 4; mt++) {
        int grow0 = m0 + wr * 64 + mt * 16 + quad * 4;
#pragma unroll
        for (int nt = 0; nt < 4; nt++) {
            int gcol = n0 + wc * 64 + nt * 16 + lm;
            float bia = bias ? bias[gcol] : 0.0f;
            f32x4 v = acc[mt][nt];
#pragma unroll
            for (int i = 0; i < 4; i++) {
                int grow = grow0 + i;
                float val = v[i] + bia;
                if (ACT == 1) val = val * 0.5f * (1.0f + erff(val * 0.70710678118654752f));
                if (ACT == 2) val = fmaxf(val, 0.0f);
                if (RESID) val += b2f(R[(size_t)grow * N + gcol]);
                if (OUTBF) ((ushort*)Cout)[(size_t)grow * N + gcol] = f2b(val);
                else       ((float*)Cout)[(size_t)grow * N + gcol]  = val;
            }
        }
    }
}

// ================= flash-style softmax attention (o1 half), MFMA ============
__global__ __launch_bounds__(256)
void attn1_k(const ushort* __restrict__ qkvt, ushort* __restrict__ O) {
    const int bn = blockIdx.x, h = blockIdx.y;
    const int tid = threadIdx.x;
    const int wave = tid >> 6, lane = tid & 63;
    const int lm = lane & 15, quad = lane >> 4;
    __shared__ __align__(16) ushort Ks[32 * 136];
    __shared__ __align__(16) ushort Vt[128 * 40];
    __shared__ __align__(16) ushort Ps[4][64 * 40];
    const ushort* base = qkvt + (size_t)bn * T_ * 2048;

    short8 aq[4][4];
#pragma unroll
    for (int mt = 0; mt < 4; mt++) {
        const ushort* qrow = base + (size_t)(wave * 64 + mt * 16 + lm) * 2048 + h * DH_;
#pragma unroll
        for (int ks = 0; ks < 4; ks++)
            aq[mt][ks] = *(const short8*)(qrow + ks * 32 + quad * 8);
    }

    f32x4 oacc[4][8];
#pragma unroll
    for (int mt = 0; mt < 4; mt++)
#pragma unroll
        for (int nt = 0; nt < 8; nt++) oacc[mt][nt] = (f32x4){0.f, 0.f, 0.f, 0.f};
    float mrow[4][4], lrow[4][4];
#pragma unroll
    for (int mt = 0; mt < 4; mt++)
#pragma unroll
        for (int i = 0; i < 4; i++) { mrow[mt][i] = -1e30f; lrow[mt][i] = 0.0f; }

    for (int kt = 0; kt < 8; kt++) {
        __syncthreads();
#pragma unroll
        for (int u = 0; u < 2; u++) {
            int ii = tid + u * 256;
            int j = ii >> 4, dc = ii & 15;
            *(uint4*)&Ks[j * 136 + dc * 8] =
                *(const uint4*)(base + (size_t)(kt * 32 + j) * 2048 + 512 + h * DH_ + dc * 8);
        }
        {
            int j = tid & 31, half = tid >> 5;
            const ushort* vrow = base + (size_t)(kt * 32 + j) * 2048 + 1024 + h * DH_ + half * 16;
            uint4 v0 = *(const uint4*)vrow;
            uint4 v1 = *(const uint4*)(vrow + 8);
            ushort e[16];
            *(uint4*)&e[0] = v0; *(uint4*)&e[8] = v1;
#pragma unroll
            for (int u = 0; u < 16; u++)
                Vt[(half * 16 + u) * 40 + j] = e[u];
        }
        __syncthreads();

        f32x4 s[4][2];
#pragma unroll
        for (int mt = 0; mt < 4; mt++)
#pragma unroll
            for (int nt = 0; nt < 2; nt++) s[mt][nt] = (f32x4){0.f, 0.f, 0.f, 0.f};
#pragma unroll
        for (int ks = 0; ks < 4; ks++) {
            short8 bk0 = *(const short8*)&Ks[lm * 136 + ks * 32 + quad * 8];
            short8 bk1 = *(const short8*)&Ks[(16 + lm) * 136 + ks * 32 + quad * 8];
#pragma unroll
            for (int mt = 0; mt < 4; mt++) {
                s[mt][0] = __builtin_amdgcn_mfma_f32_16x16x32_bf16(aq[mt][ks], bk0, s[mt][0], 0, 0, 0);
                s[mt][1] = __builtin_amdgcn_mfma_f32_16x16x32_bf16(aq[mt][ks], bk1, s[mt][1], 0, 0, 0);
            }
        }

#pragma unroll
        for (int mt = 0; mt < 4; mt++) {
#pragma unroll
            for (int i = 0; i < 4; i++) {
                float v0 = s[mt][0][i] * SCALE_;
                float v1 = s[mt][1][i] * SCALE_;
                float rmax = fmaxf(v0, v1);
#pragma unroll
                for (int mk = 1; mk < 16; mk <<= 1)
                    rmax = fmaxf(rmax, __shfl_xor(rmax, mk));
                float mold = mrow[mt][i];
                float mnew = fmaxf(mold, rmax);
                float alpha = __expf(mold - mnew);
                float p0 = __expf(v0 - mnew);
                float p1 = __expf(v1 - mnew);
                float rs = p0 + p1;
#pragma unroll
                for (int mk = 1; mk < 16; mk <<= 1)
                    rs += __shfl_xor(rs, mk);
                lrow[mt][i] = lrow[mt][i] * alpha + rs;
                mrow[mt][i] = mnew;
#pragma unroll
                for (int nt = 0; nt < 8; nt++) {
                    oacc[mt][nt][i] *= alpha;
                }
                int prow = mt * 16 + quad * 4 + i;
                Ps[wave][prow * 40 + lm]      = f2b(p0);
                Ps[wave][prow * 40 + 16 + lm] = f2b(p1);
            }
        }

        short8 ap[4];
#pragma unroll
        for (int mt = 0; mt < 4; mt++)
            ap[mt] = *(const short8*)&Ps[wave][(mt * 16 + lm) * 40 + quad * 8];
#pragma unroll
        for (int nt = 0; nt < 8; nt++) {
            short8 bv = *(const short8*)&Vt[(nt * 16 + lm) * 40 + quad * 8];
#pragma unroll
            for (int mt = 0; mt < 4; mt++)
                oacc[mt][nt] = __builtin_amdgcn_mfma_f32_16x16x32_bf16(ap[mt], bv, oacc[mt][nt], 0, 0, 0);
        }
    }

#pragma unroll
    for (int mt = 0; mt < 4; mt++) {
#pragma unroll
        for (int i = 0; i < 4; i++) {
            int row = wave * 64 + mt * 16 + quad * 4 + i;
            float rinv = 1.0f / lrow[mt][i];
#pragma unroll
            for (int nt = 0; nt < 8; nt++) {
                int d = nt * 16 + lm;
                O[((size_t)bn * T_ + row) * 1024 + h * 256 + d] =
                    f2b(oacc[mt][nt][i] * rinv);
            }
        }
    }
}

// ================= decay attention (o2 half): o2 = A2 @ T, batched over bn ==
__global__ __launch_bounds__(256)
void attn2_k(const ushort* __restrict__ A2, const ushort* __restrict__ qkvt,
             ushort* __restrict__ O) {
    __shared__ __align__(16) ushort As[128 * LDT];
    __shared__ __align__(16) ushort Bs[128 * 48];
    const int tid = threadIdx.x;
    const int bn = blockIdx.z;
    const int m0 = blockIdx.y * 128;
    const int n0 = blockIdx.x * 128;
    const int lane = tid & 63, wave = tid >> 6;
    const int wr = wave >> 1, wc = wave & 1;
    const int lm = lane & 15, quad = lane >> 4;
    const ushort* tbase = qkvt + (size_t)bn * T_ * 2048 + 1536;
    const int r = tid >> 1, c0 = (tid & 1) * 2;

    f32x4 acc[4][4];
#pragma unroll
    for (int mt = 0; mt < 4; mt++)
#pragma unroll
        for (int nt = 0; nt < 4; nt++) acc[mt][nt] = (f32x4){0.f, 0.f, 0.f, 0.f};

    for (int k0 = 0; k0 < 256; k0 += 32) {
        const ushort* Arow = A2 + (size_t)(m0 + r) * 256 + k0;
        *(uint4*)&As[r * LDT + c0 * 8]       = *(const uint4*)(Arow + c0 * 8);
        *(uint4*)&As[r * LDT + (c0 + 1) * 8] = *(const uint4*)(Arow + (c0 + 1) * 8);
        {
            int kr = tid & 31, np = tid >> 5;
            const ushort* trow = tbase + (size_t)(k0 + kr) * 2048 + n0 + np * 16;
            uint4 v0 = *(const uint4*)trow;
            uint4 v1 = *(const uint4*)(trow + 8);
            ushort e[16];
            *(uint4*)&e[0] = v0; *(uint4*)&e[8] = v1;
#pragma unroll
            for (int u = 0; u < 16; u++)
                Bs[(np * 16 + u) * 48 + kr] = e[u];
        }
        __syncthreads();
        short8 af[4], bf[4];
#pragma unroll
        for (int mt = 0; mt < 4; mt++)
            af[mt] = *(const short8*)&As[(wr * 64 + mt * 16 + lm) * LDT + quad * 8];
#pragma unroll
        for (int nt = 0; nt < 4; nt++)
            bf[nt] = *(const short8*)&Bs[(wc * 64 + nt * 16 + lm) * 48 + quad * 8];
#pragma unroll
        for (int mt = 0; mt < 4; mt++)
#pragma unroll
            for (int nt = 0; nt < 4; nt++)
                acc[mt][nt] = __builtin_amdgcn_mfma_f32_16x16x32_bf16(
                    af[mt], bf[nt], acc[mt][nt], 0, 0, 0);
        __syncthreads();
    }

#pragma unroll
    for (int mt = 0; mt < 4; mt++) {
        int row0 = m0 + wr * 64 + mt * 16 + quad * 4;
#pragma unroll
        for (int nt = 0; nt < 4; nt++) {
            int n = n0 + wc * 64 + nt * 16 + lm;
            int h = n >> 7, d = n & 127;
#pragma unroll
            for (int i = 0; i < 4; i++) {
                int row = row0 + i;
                O[((size_t)bn * T_ + row) * 1024 + h * 256 + 128 + d] =
                    f2b(acc[mt][nt][i]);
            }
        }
    }
}

// ============ head stage 1: x1 = h @ c1W^T + c1b  (M x 32, K=512, MFMA) =====
#define BLD 520
__global__ __launch_bounds__(256)
void head1_k(const ushort* __restrict__ Hb, const ushort* __restrict__ c1Wb,
             const float* __restrict__ c1b, float* __restrict__ X1) {
    __shared__ __align__(16) ushort As[128 * LDT];
    __shared__ __align__(16) ushort Bs[32 * BLD];
    const int tid = threadIdx.x;
    const int lane = tid & 63, wave = tid >> 6;
    const int lm = lane & 15, quad = lane >> 4;
    const int m0 = blockIdx.x * 128;
#pragma unroll
    for (int u = 0; u < 8; u++) {
        int ii = tid + u * 256;
        int nrow = ii >> 6;
        int koff = (ii & 63) * 8;
        *(uint4*)&Bs[nrow * BLD + koff] = *(const uint4*)(c1Wb + nrow * 512 + koff);
    }
    f32x4 acc[2][2];
#pragma unroll
    for (int mt = 0; mt < 2; mt++)
#pragma unroll
        for (int nt = 0; nt < 2; nt++) acc[mt][nt] = (f32x4){0.f, 0.f, 0.f, 0.f};

    const int r = tid >> 1, half = tid & 1;
    for (int k0 = 0; k0 < 512; k0 += 32) {
        const ushort* s = Hb + (size_t)(m0 + r) * 512 + k0 + half * 16;
        uint4 v0 = *(const uint4*)s;
        uint4 v1 = *(const uint4*)(s + 8);
        __syncthreads();
        *(uint4*)&As[r * LDT + half * 16]     = v0;
        *(uint4*)&As[r * LDT + half * 16 + 8] = v1;
        __syncthreads();
        short8 af[2], bf[2];
#pragma unroll
        for (int mt = 0; mt < 2; mt++)
            af[mt] = *(const short8*)&As[(wave * 32 + mt * 16 + lm) * LDT + quad * 8];
#pragma unroll
        for (int nt = 0; nt < 2; nt++)
            bf[nt] = *(const short8*)&Bs[(nt * 16 + lm) * BLD + k0 + quad * 8];
#pragma unroll
        for (int mt = 0; mt < 2; mt++)
#pragma unroll
            for (int nt = 0; nt < 2; nt++)
                acc[mt][nt] = __builtin_amdgcn_mfma_f32_16x16x32_bf16(
                    af[mt], bf[nt], acc[mt][nt], 0, 0, 0);
    }
#pragma unroll
    for (int mt = 0; mt < 2; mt++) {
        int row0 = m0 + wave * 32 + mt * 16 + quad * 4;
#pragma unroll
        for (int nt = 0; nt < 2; nt++) {
            int col = nt * 16 + lm;
            float bia = c1b[col];
#pragma unroll
            for (int i = 0; i < 4; i++)
                X1[(size_t)(row0 + i) * 32 + col] = acc[mt][nt][i] + bia;
        }
    }
}

// ============ head stage 2: one thread per (bn,t) row ========================
__global__ __launch_bounds__(256)
void head2_k(const float* __restrict__ X1, int bn_base, int M,
             const float* __restrict__ g1, const float* __restrict__ b1,
             const float* __restrict__ m1, const float* __restrict__ v1,
             const float* __restrict__ c2W, const float* __restrict__ c2b,
             const float* __restrict__ g2, const float* __restrict__ b2,
             const float* __restrict__ m2, const float* __restrict__ v2,
             const float* __restrict__ c3W, const float* __restrict__ c3b,
             float* __restrict__ sum_dist, float* __restrict__ sum_score) {
    int row = blockIdx.x * 256 + threadIdx.x;
    if (row >= M) return;
    float x1[32], y1[32];
    const float* xr = X1 + (size_t)row * 32;
#pragma unroll
    for (int c = 0; c < 32; c++) x1[c] = xr[c];
    float d1 = 0.0f;
#pragma unroll
    for (int c = 0; c < 32; c++) {
        float dd = x1[c] - m1[c];
        d1 += dd * dd / v1[c];
        y1[c] = fmaxf(0.0f, dd * rsqrtf(v1[c] + LEPS) * g1[c] + b1[c]);
    }
    float d2 = 0.0f, sc = c3b[0];
#pragma unroll
    for (int o = 0; o < 16; o++) {
        float acc = c2b[o];
        const float* wr = c2W + o * 32;
#pragma unroll
        for (int c = 0; c < 32; c++) acc += wr[c] * y1[c];
        float dd = acc - m2[o];
        d2 += dd * dd / v2[o];
        float y2 = fmaxf(0.0f, dd * rsqrtf(v2[o] + LEPS) * g2[o] + b2[o]);
        sc += c3W[o] * y2;
    }
    float dist = sqrtf(d1) + sqrtf(d2);
    sc = 1.0f / (1.0f + expf(-sc));
    int bn = bn_base + (row >> 8);
    int t = row & 255;
    int b = bn / 10;
    atomicAdd(&sum_dist[b * T_ + t], dist);
    atomicAdd(&sum_score[b * T_ + t], sc);
}

// --------------------------------------------------------------- final out
__global__ void combine_k(const float* __restrict__ sd, const float* __restrict__ ss,
                          float* __restrict__ out) {
    int i = blockIdx.x * 256 + threadIdx.x;
    if (i < 16 * T_) out[i] = (sd[i] * 0.1f) * (ss[i] * 0.1f);
}

// ===========================================================================
extern "C" void kernel_launch(void* const* d_in, const int* in_sizes, int n_in,
                              void* d_out, int out_size, void* d_ws, size_t ws_size,
                              hipStream_t stream) {
    const float* x     = (const float*)d_in[0];
    const float* W_emb = (const float*)d_in[1];
    const float* b_emb = (const float*)d_in[2];
    const float* ln1_g = (const float*)d_in[3];
    const float* ln1_b = (const float*)d_in[4];
    const float* W_qkv = (const float*)d_in[5];
    const float* W_o   = (const float*)d_in[6];
    const float* b_o   = (const float*)d_in[7];
    const float* ln2_g = (const float*)d_in[8];
    const float* ln2_b = (const float*)d_in[9];
    const float* W_f1  = (const float*)d_in[10];
    const float* b_f1  = (const float*)d_in[11];
    const float* W_f2  = (const float*)d_in[12];
    const float* b_f2  = (const float*)d_in[13];
    const float* c1_W  = (const float*)d_in[14];
    const float* c1_b  = (const float*)d_in[15];
    const float* bn1_g = (const float*)d_in[16];
    const float* bn1_b = (const float*)d_in[17];
    const float* bn1_m = (const float*)d_in[18];
    const float* bn1_v = (const float*)d_in[19];
    const float* c2_W  = (const float*)d_in[20];
    const float* c2_b  = (const float*)d_in[21];
    const float* bn2_g = (const float*)d_in[22];
    const float* bn2_b = (const float*)d_in[23];
    const float* bn2_m = (const float*)d_in[24];
    const float* bn2_v = (const float*)d_in[25];
    const float* c3_W  = (const float*)d_in[26];
    const float* c3_b  = (const float*)d_in[27];
    float* out = (float*)d_out;

    // ---------------- workspace layout (runtime-chunked over bn) ----------
    char* p = (char*)d_ws;
    auto alloc = [&](size_t bytes) -> char* {
        char* q = p; p += (bytes + 255) & ~(size_t)255; return q;
    };
    ushort* wEmb = (ushort*)alloc((size_t)C_ * 3072 * 2);
    ushort* wQkv = (ushort*)alloc((size_t)2 * 2048 * 512 * 2);
    ushort* wO   = (ushort*)alloc((size_t)2 * 512 * 1024 * 2);
    ushort* wF1  = (ushort*)alloc((size_t)2 * 512 * 512 * 2);
    ushort* wF2  = (ushort*)alloc((size_t)2 * 512 * 512 * 2);
    ushort* A2bf = (ushort*)alloc((size_t)256 * 256 * 2);
    ushort* c1Wb = (ushort*)alloc((size_t)32 * 512 * 2);
    float*  s256      = (float*)alloc(256 * 4);
    float*  sum_dist  = (float*)alloc(4096 * 4);
    float*  sum_score = (float*)alloc(4096 * 4);
    size_t fixedB = (size_t)(p - (char*)d_ws);

    // per-row bytes: xbp 2064 + h 1024 + z 1024 + qkvt 4096 + o 2048 + X1 128 = 10384
    int CH = 8;
    const int cands[7] = {160, 80, 40, 32, 20, 16, 10};
    for (int ci = 0; ci < 7; ci++) {
        size_t per = (size_t)cands[ci] * 256 * 10384 + 16384;
        if (fixedB + per <= ws_size) { CH = cands[ci]; break; }
    }
    const int MR = CH * 256;
    ushort* xbp  = (ushort*)alloc((size_t)CH * XROW * 2);
    ushort* h    = (ushort*)alloc((size_t)MR * 512 * 2);
    ushort* z    = (ushort*)alloc((size_t)MR * 512 * 2);
    ushort* qkvt = (ushort*)alloc((size_t)MR * 2048 * 2);
    ushort* o    = (ushort*)alloc((size_t)MR * 1024 * 2);
    ushort* g    = o;
    float*  X1   = (float*)alloc((size_t)MR * 32 * 4);

    // ---------------- once-per-launch prep ----------------
    zero_k<<<(8192 + 255) / 256, 256, 0, stream>>>(sum_dist, 8192);
    a2_colsum_k<<<1, 256, 0, stream>>>(s256);
    a2fill_k<<<256, 256, 0, stream>>>(s256, A2bf);
    wemb_k<<<(C_ * 3072 + 255) / 256, 256, 0, stream>>>(W_emb, wEmb);
    bcvt_k<<<(32 * 512 + 255) / 256, 256, 0, stream>>>(c1_W, c1Wb, 32 * 512);
    for (int l = 0; l < 2; l++) {
        tconv_k<<<dim3(512 / 32, 2048 / 32), 256, 0, stream>>>(
            W_qkv + (size_t)l * 512 * 2048, wQkv + (size_t)l * 2048 * 512, 512, 2048);
        tconv_k<<<dim3(1024 / 32, 512 / 32), 256, 0, stream>>>(
            W_o + (size_t)l * 1024 * 512, wO + (size_t)l * 512 * 1024, 1024, 512);
        tconv_k<<<dim3(512 / 32, 512 / 32), 256, 0, stream>>>(
            W_f1 + (size_t)l * 512 * 512, wF1 + (size_t)l * 512 * 512, 512, 512);
        tconv_k<<<dim3(512 / 32, 512 / 32), 256, 0, stream>>>(
            W_f2 + (size_t)l * 512 * 512, wF2 + (size_t)l * 512 * 512, 512, 512);
    }

    // ---------------- pipeline, chunked over bn ----------------
    for (int cs = 0; cs < BNB; cs += CH) {
        const float* xc = x + (size_t)cs * T_ * D_;

        // x chunk -> bf16 padded + zero pad rows
        int n4 = MR * 1024 / 4;
        xcvt_k<<<(n4 + 255) / 256, 256, 0, stream>>>(xc, xbp, n4);
        xpad_k<<<(CH * 1024 + 255) / 256, 256, 0, stream>>>(xbp, CH);

        // conv1d(k=3,pad=1)+ReLU as implicit-im2row MFMA GEMM -> h bf16
        gemm256_k<1, 2, 0, 1><<<dim3(512 / 256, MR / 256), 512, 0, stream>>>(
            nullptr, wEmb, b_emb, nullptr, h, MR, 512, 3072, xbp);

        for (int l = 0; l < 2; l++) {
            ln_k<<<MR / 4, 256, 0, stream>>>(h, ln1_g + l * C_, ln1_b + l * C_, z);
            gemm256_k<0, 0, 0, 1><<<dim3(2048 / 256, MR / 256), 512, 0, stream>>>(
                z, wQkv + (size_t)l * 2048 * 512, nullptr, nullptr, qkvt,
                MR, 2048, 512, nullptr);
            attn1_k<<<dim3(CH, H_), 256, 0, stream>>>(qkvt, o);
            attn2_k<<<dim3(4, 2, CH), 256, 0, stream>>>(A2bf, qkvt, o);
            gemm_k<0, 0, 1, 1><<<dim3(512 / 128, MR / 128), 256, 0, stream>>>(
                o, wO + (size_t)l * 512 * 1024, b_o + l * C_, h, h,
                MR, 512, 1024, nullptr);
            ln_k<<<MR / 4, 256, 0, stream>>>(h, ln2_g + l * C_, ln2_b + l * C_, z);
            gemm_k<0, 1, 0, 1><<<dim3(512 / 128, MR / 128), 256, 0, stream>>>(
                z, wF1 + (size_t)l * 512 * 512, b_f1 + l * C_, nullptr, g,
                MR, 512, 512, nullptr);
            gemm_k<0, 0, 1, 1><<<dim3(512 / 128, MR / 128), 256, 0, stream>>>(
                g, wF2 + (size_t)l * 512 * 512, b_f2 + l * C_, h, h,
                MR, 512, 512, nullptr);
        }

        head1_k<<<MR / 128, 256, 0, stream>>>(h, c1Wb, c1_b, X1);
        head2_k<<<MR / 256, 256, 0, stream>>>(
            X1, cs, MR, bn1_g, bn1_b, bn1_m, bn1_v,
            c2_W, c2_b, bn2_g, bn2_b, bn2_m, bn2_v, c3_W, c3_b,
            sum_dist, sum_score);
    }

    combine_k<<<16, 256, 0, stream>>>(sum_dist, sum_score, out);
}

// Round 3
// 1558.971 us; speedup vs baseline: 1.1312x; 1.1312x over previous
//
#include <hip/hip_runtime.h>
#include <math.h>

#define T_    256
#define D_    1024
#define C_    512
#define H_    4
#define DH_   128
#define BNB   160
#define LEPS  1e-5f
#define INV_E 0.36787944117144233f
#define SCALE_ 0.08838834764831845f   // 1/sqrt(128)
#define LDT   40                      // padded LDS stride (attn/head kernels)
#define XROW  264192                  // padded x row block: 258*1024 elems per bn

typedef unsigned short ushort;
typedef unsigned int   uint;
typedef __attribute__((ext_vector_type(8))) short short8;   // 8 bf16 (4 VGPRs)
typedef __attribute__((ext_vector_type(4))) float f32x4;

__device__ __forceinline__ ushort f2b(float f) {            // fp32 -> bf16 RNE
    uint u = __float_as_uint(f);
    u += 0x7fffu + ((u >> 16) & 1u);
    return (ushort)(u >> 16);
}
__device__ __forceinline__ float b2f(ushort u) {
    return __uint_as_float(((uint)u) << 16);
}
__device__ __forceinline__ uint pk(float a, float b) {
    return (uint)f2b(a) | ((uint)f2b(b) << 16);
}
// async global->LDS DMA, 16B/lane; lds dest is wave-uniform base (+lane*16 by HW)
__device__ __forceinline__ void gl2lds(const void* g, void* l) {
    __builtin_amdgcn_global_load_lds(
        (const __attribute__((address_space(1))) void*)g,
        (__attribute__((address_space(3))) void*)l, 16, 0, 0);
}

// ---------------------------------------------------------------- zero fill
__global__ void zero_k(float* __restrict__ p, int n) {
    int i = blockIdx.x * 256 + threadIdx.x;
    if (i < n) p[i] = 0.0f;
}

// ---------------- x fp32 -> bf16 into padded layout [bn][258][1024], data at row t+1
__global__ void xcvt_k(const float* __restrict__ src, ushort* __restrict__ dst, int n4) {
    int i = blockIdx.x * 256 + threadIdx.x;
    if (i < n4) {
        float4 f = ((const float4*)src)[i];
        uint2 v;
        v.x = pk(f.x, f.y);
        v.y = pk(f.z, f.w);
        int e   = i * 4;
        int bn  = e >> 18;            // 262144 elems per bn
        int rem = e & 262143;
        ((uint2*)(dst + (size_t)bn * XROW + 1024 + rem))[0] = v;
    }
}

// ---------------- zero the pad rows (rows 0 and 257 of each bn)
__global__ void xpad_k(ushort* __restrict__ dst, int nbn) {
    int i = blockIdx.x * 256 + threadIdx.x;
    if (i >= nbn * 1024) return;
    int bn = i >> 10, j = i & 1023;
    int r = j >> 9, c = j & 511;
    uint* base = (uint*)(dst + (size_t)bn * XROW);
    base[(r ? (XROW - 1024) / 2 : 0) + c] = 0u;
}

// ---------------- tiled transpose+convert: src (K,N) fp32 -> dst (N,K) bf16
__global__ __launch_bounds__(256)
void tconv_k(const float* __restrict__ src, ushort* __restrict__ dst,
             int K, int N) {
    __shared__ float tile[32][33];
    int kb = blockIdx.x * 32, nb = blockIdx.y * 32;
    int tx = threadIdx.x & 31, ty = threadIdx.x >> 5;   // 32 x 8
#pragma unroll
    for (int i = 0; i < 32; i += 8)
        tile[ty + i][tx] = src[(size_t)(kb + ty + i) * N + nb + tx];
    __syncthreads();
#pragma unroll
    for (int i = 0; i < 32; i += 8)
        dst[(size_t)(nb + ty + i) * K + kb + tx] = f2b(tile[tx][ty + i]);
}

// ---------------- elementwise fp32 -> bf16 convert
__global__ void bcvt_k(const float* __restrict__ src, ushort* __restrict__ dst, int n) {
    int i = blockIdx.x * 256 + threadIdx.x;
    if (i < n) dst[i] = f2b(src[i]);
}

// -------- W_emb (C,1024,3) -> bf16 [C][3072] with k = dt*1024+ci ordering
__global__ void wemb_k(const float* __restrict__ W, ushort* __restrict__ Wt) {
    int idx = blockIdx.x * 256 + threadIdx.x;
    if (idx >= C_ * 3072) return;
    int c = idx / 3072, k = idx % 3072;
    int dt = k >> 10, ci = k & 1023;
    Wt[idx] = f2b(W[(size_t)c * 3072 + ci * 3 + dt]);
}

// -------------------------------- s[j] = sum_k exp(-|j-k|/e)  (a2 col sums)
__global__ void a2_colsum_k(float* __restrict__ s) {
    int j = threadIdx.x;
    float acc = 0.0f;
    for (int k = 0; k < T_; k++) acc += expf(-fabsf((float)(j - k)) * INV_E);
    s[j] = acc;
}

// -------------------------------- A2 bf16 [i][j] = exp(-|i-j|/e)/s[j]
__global__ void a2fill_k(const float* __restrict__ s, ushort* __restrict__ A2) {
    int i = blockIdx.x, j = threadIdx.x;
    A2[i * 256 + j] = f2b(expf(-fabsf((float)(i - j)) * INV_E) / s[j]);
}

// ------------------- LayerNorm: one wave per row, shuffle-only reductions
__global__ __launch_bounds__(256)
void ln_k(const ushort* __restrict__ X, const float* __restrict__ g,
          const float* __restrict__ b, ushort* __restrict__ Z) {
    int row  = blockIdx.x * 4 + (threadIdx.x >> 6);
    int lane = threadIdx.x & 63;
    const ushort* xr = X + (size_t)row * C_ + lane * 8;
    uint4 raw = *(const uint4*)xr;
    float f[8];
    f[0] = __uint_as_float(raw.x << 16); f[1] = __uint_as_float(raw.x & 0xffff0000u);
    f[2] = __uint_as_float(raw.y << 16); f[3] = __uint_as_float(raw.y & 0xffff0000u);
    f[4] = __uint_as_float(raw.z << 16); f[5] = __uint_as_float(raw.z & 0xffff0000u);
    f[6] = __uint_as_float(raw.w << 16); f[7] = __uint_as_float(raw.w & 0xffff0000u);
    float s = 0.0f, s2 = 0.0f;
#pragma unroll
    for (int u = 0; u < 8; u++) { s += f[u]; s2 += f[u] * f[u]; }
#pragma unroll
    for (int m = 1; m < 64; m <<= 1) {
        s  += __shfl_xor(s, m);
        s2 += __shfl_xor(s2, m);
    }
    float mean = s * (1.0f / C_);
    float var  = s2 * (1.0f / C_) - mean * mean;
    float rinv = rsqrtf(var + LEPS);
    const float* gp = g + lane * 8;
    const float* bp = b + lane * 8;
    float4 g0 = *(const float4*)gp, g1 = *(const float4*)(gp + 4);
    float4 b0 = *(const float4*)bp, b1 = *(const float4*)(bp + 4);
    uint4 outv;
    outv.x = pk((f[0]-mean)*rinv*g0.x+b0.x, (f[1]-mean)*rinv*g0.y+b0.y);
    outv.y = pk((f[2]-mean)*rinv*g0.z+b0.z, (f[3]-mean)*rinv*g0.w+b0.w);
    outv.z = pk((f[4]-mean)*rinv*g1.x+b1.x, (f[5]-mean)*rinv*g1.y+b1.y);
    outv.w = pk((f[6]-mean)*rinv*g1.z+b1.z, (f[7]-mean)*rinv*g1.w+b1.w);
    *(uint4*)(Z + (size_t)row * C_ + lane * 8) = outv;
}

// ======= bf16 MFMA GEMM, 256x256 tile, BK=64, 8-phase counted-vmcnt =========
// (R1-measured schedule: conv 186us, MfmaUtil 28, bank conflicts 0)
// C(MxN) = A(MxK,bf16) @ B'(NxK,bf16)  [+bias] [ACT 1=gelu 2=relu] [+R bf16]
// CONV=1: A implicit im2row of padded Xp ([bn][258][1024], zero pad rows)
// Schedule (per K-tile, 4 phases; 2 K-tiles double-buffered in LDS):
//   p1: ds_read A(mf0-3)+B(nf0-1) | stage B1(t+1) | vmcnt(8) bar lgk0 | 16 MFMA | bar
//   p2: ds_read B(nf2-3)          | stage A1(t+1) | vmcnt(8) bar lgk0 | 16 MFMA | bar
//   p3: ds_read A(mf4-7)          | stage A0(t+2) |          bar lgk0 | 16 MFMA | bar
//   p4: (regs reused)             | stage B0(t+2) | vmcnt(8) bar      | 16 MFMA | bar
// vmcnt(8) = 4 half-tiles (2 loads each) allowed in flight.  LDS XOR-swizzle
// slot16^=(row&7) applied BOTH sides (pre-swizzled source, rule 21).

#define VMW_8 asm volatile("s_waitcnt vmcnt(8)" ::: "memory")
#define VMW_4 asm volatile("s_waitcnt vmcnt(4)" ::: "memory")
#define VMW_2 asm volatile("s_waitcnt vmcnt(2)" ::: "memory")
#define VMW_0 asm volatile("s_waitcnt vmcnt(0)" ::: "memory")
#define VMW_N
#define BAR() __builtin_amdgcn_s_barrier()
#define LGK0() do { asm volatile("s_waitcnt lgkmcnt(0)" ::: "memory"); \
                    __builtin_amdgcn_sched_barrier(0); } while (0)

#define TILE(kt, S1, S2, S3, S4, W1, W2, W4) do {                              \
    /* ---- phase 1: quadrant (mf0-3, nf0-1) ---- */                           \
    _Pragma("unroll") for (int mf = 0; mf < 4; mf++)                           \
      _Pragma("unroll") for (int ks = 0; ks < 2; ks++)                         \
        af[mf][ks] = ldA(kt, mf, ks);                                          \
    _Pragma("unroll") for (int nf = 0; nf < 2; nf++)                           \
      _Pragma("unroll") for (int ks = 0; ks < 2; ks++)                         \
        bf[nf][ks] = ldB(kt, nf, ks);                                          \
    if (S1) stageB((kt) + 1, 1);                                               \
    VMW_##W1; BAR(); LGK0();                                                   \
    __builtin_amdgcn_s_setprio(1);                                             \
    _Pragma("unroll") for (int ks = 0; ks < 2; ks++)                           \
      _Pragma("unroll") for (int mf = 0; mf < 4; mf++)                         \
        _Pragma("unroll") for (int nf = 0; nf < 2; nf++)                       \
          acc[mf][nf] = __builtin_amdgcn_mfma_f32_16x16x32_bf16(               \
              af[mf][ks], bf[nf][ks], acc[mf][nf], 0, 0, 0);                   \
    __builtin_amdgcn_s_setprio(0);                                             \
    BAR();                                                                     \
    /* ---- phase 2: quadrant (mf0-3, nf2-3), A regs reused ---- */            \
    _Pragma("unroll") for (int nf = 2; nf < 4; nf++)                           \
      _Pragma("unroll") for (int ks = 0; ks < 2; ks++)                         \
        bf[nf][ks] = ldB(kt, nf, ks);                                          \
    if (S2) stageA((kt) + 1, 1);                                               \
    VMW_##W2; BAR(); LGK0();                                                   \
    __builtin_amdgcn_s_setprio(1);                                             \
    _Pragma("unroll") for (int ks = 0; ks < 2; ks++)                           \
      _Pragma("unroll") for (int mf = 0; mf < 4; mf++)                         \
        _Pragma("unroll") for (int nf = 2; nf < 4; nf++)                       \
          acc[mf][nf] = __builtin_amdgcn_mfma_f32_16x16x32_bf16(               \
              af[mf][ks], bf[nf][ks], acc[mf][nf], 0, 0, 0);                   \
    __builtin_amdgcn_s_setprio(0);                                             \
    BAR();                                                                     \
    /* ---- phase 3: quadrant (mf4-7, nf0-1) ---- */                           \
    _Pragma("unroll") for (int mf = 0; mf < 4; mf++)                           \
      _Pragma("unroll") for (int ks = 0; ks < 2; ks++)                         \
        af[mf][ks] = ldA(kt, mf + 4, ks);                                      \
    if (S3) stageA((kt) + 2, 0);                                               \
    BAR(); LGK0();                                                             \
    __builtin_amdgcn_s_setprio(1);                                             \
    _Pragma("unroll") for (int ks = 0; ks < 2; ks++)                           \
      _Pragma("unroll") for (int mf = 0; mf < 4; mf++)                         \
        _Pragma("unroll") for (int nf = 0; nf < 2; nf++)                       \
          acc[mf + 4][nf] = __builtin_amdgcn_mfma_f32_16x16x32_bf16(           \
              af[mf][ks], bf[nf][ks], acc[mf + 4][nf], 0, 0, 0);               \
    __builtin_amdgcn_s_setprio(0);                                             \
    BAR();                                                                     \
    /* ---- phase 4: quadrant (mf4-7, nf2-3), all regs reused ---- */          \
    if (S4) stageB((kt) + 2, 0);                                               \
    VMW_##W4; BAR();                                                           \
    __builtin_amdgcn_s_setprio(1);                                             \
    _Pragma("unroll") for (int ks = 0; ks < 2; ks++)                           \
      _Pragma("unroll") for (int mf = 0; mf < 4; mf++)                         \
        _Pragma("unroll") for (int nf = 2; nf < 4; nf++)                       \
          acc[mf + 4][nf] = __builtin_amdgcn_mfma_f32_16x16x32_bf16(           \
              af[mf][ks], bf[nf][ks], acc[mf + 4][nf], 0, 0, 0);               \
    __builtin_amdgcn_s_setprio(0);                                             \
    BAR();                                                                     \
} while (0)

template<int CONV, int ACT, int RESID, int OUTBF>
__global__ __launch_bounds__(512, 2)
void gemm256_k(const ushort* __restrict__ A, const ushort* __restrict__ B,
               const float* __restrict__ bias, const ushort* __restrict__ R,
               void* __restrict__ Cout, int M, int N, int K,
               const ushort* __restrict__ Xp) {
    // LDS: [buf(2)][half(2)][128 rows][64 cols] bf16 for A and B  (128 KiB)
    __shared__ __align__(16) ushort As[32768];
    __shared__ __align__(16) ushort Bs[32768];
    const int tid  = threadIdx.x;
    const int wave = tid >> 6, lane = tid & 63;
    const int wm = wave >> 2, wn = wave & 3;        // 2 x 4 wave grid
    const int lm = lane & 15, quad = lane >> 4;

    // ---- XCD-aware swizzle: all N-panels of one M-tile on one XCD ----
    const int NP = gridDim.x, My = gridDim.y;
    int m_idx, n_idx;
    if ((My & 7) == 0) {
        int bid = blockIdx.y * NP + blockIdx.x;
        m_idx = (bid & 7) + 8 * (bid / (8 * NP));
        n_idx = (bid >> 3) % NP;
    } else {
        m_idx = blockIdx.y; n_idx = blockIdx.x;
    }
    const int m0 = m_idx * 256, n0 = n_idx * 256;

    // staging lane geometry: 8 lanes per row, pre-swizzled source column
    const int srow = lane >> 3;                 // row-in-8 (== tile row mod 8)
    const int scol = ((lane & 7) ^ srow) << 3;  // swizzled source elem offset

    auto stageA = [&](int kt, int half) {
        ushort* lds = As + (((kt & 1) * 2 + half) << 13) + (wave << 9);
        int r0 = half * 128 + wave * 8 + srow;
        if (CONV) {
            int k0 = kt << 6;
            int dt = k0 >> 10;
            int cb = (k0 & 1023) + scol;
            int g0 = m0 + r0;
            gl2lds(Xp + (size_t)(g0 >> 8) * XROW + ((g0 & 255) + dt) * 1024 + cb, lds);
            int g1 = g0 + 64;
            gl2lds(Xp + (size_t)(g1 >> 8) * XROW + ((g1 & 255) + dt) * 1024 + cb, lds + 4096);
        } else {
            const ushort* ga = A + (size_t)(m0 + r0) * K + (kt << 6) + scol;
            gl2lds(ga, lds);
            gl2lds(ga + (size_t)64 * K, lds + 4096);
        }
    };
    auto stageB = [&](int kt, int half) {
        ushort* lds = Bs + (((kt & 1) * 2 + half) << 13) + (wave << 9);
        const ushort* gb = B + (size_t)(n0 + half * 128 + wave * 8 + srow) * K
                             + (kt << 6) + scol;
        gl2lds(gb, lds);
        gl2lds(gb + (size_t)64 * K, lds + 4096);
    };

    // fragment loads (swizzled ds_read, matches staged layout)
    auto ldA = [&](int kt, int mf, int ks) -> short8 {
        int r = wm * 16 + mf * 32 + lm;             // tile row (mf interleaved)
        int slot = (quad + ks * 4) ^ (lm & 7);
        return *(const short8*)&As[(((kt & 1) * 2 + (r >> 7)) << 13)
                                   + (r & 127) * 64 + slot * 8];
    };
    auto ldB = [&](int kt, int nf, int ks) -> short8 {
        int r = wn * 16 + nf * 64 + lm;             // tile col (nf interleaved)
        int slot = (quad + ks * 4) ^ (lm & 7);
        return *(const short8*)&Bs[(((kt & 1) * 2 + (r >> 7)) << 13)
                                   + (r & 127) * 64 + slot * 8];
    };

    short8 af[4][2], bf[4][2];
    f32x4 acc[8][4];
#pragma unroll
    for (int mf = 0; mf < 8; mf++)
#pragma unroll
        for (int nf = 0; nf < 4; nf++) acc[mf][nf] = (f32x4){0.f, 0.f, 0.f, 0.f};

    const int NT = K >> 6;
    // prologue: issue order A0(0),B0(0),B1(0),A1(0),A0(1),B0(1)
    stageA(0, 0); stageB(0, 0); stageB(0, 1); stageA(0, 1);
    stageA(1, 0); stageB(1, 0);
    VMW_8;           // 12 loads out -> wait to 8: A0(0),B0(0) landed
    BAR();

    for (int kt = 0; kt < NT - 2; kt++)
        TILE(kt, 1, 1, 1, 1, 8, 8, 8);
    TILE(NT - 2, 1, 1, 0, 0, 8, 8, 4);
    TILE(NT - 1, 0, 0, 0, 0, 2, 0, N);

    // ---- epilogue ----
#pragma unroll
    for (int mf = 0; mf < 8; mf++) {
        int grow0 = m0 + wm * 16 + mf * 32 + quad * 4;
#pragma unroll
        for (int nf = 0; nf < 4; nf++) {
            int gcol = n0 + wn * 16 + nf * 64 + lm;
            float bia = bias ? bias[gcol] : 0.0f;
            f32x4 v = acc[mf][nf];
#pragma unroll
            for (int i = 0; i < 4; i++) {
                int grow = grow0 + i;
                float val = v[i] + bia;
                if (ACT == 1) val = val * 0.5f * (1.0f + erff(val * 0.70710678118654752f));
                if (ACT == 2) val = fmaxf(val, 0.0f);
                if (RESID) val += b2f(R[(size_t)grow * N + gcol]);
                if (OUTBF) ((ushort*)Cout)[(size_t)grow * N + gcol] = f2b(val);
                else       ((float*)Cout)[(size_t)grow * N + gcol]  = val;
            }
        }
    }
}

// ============== bf16 MFMA GEMM, 128x128 tile, BK=32 (R0-proven path) ========
// Balanced 1280-block grid for N=512 gemms (wo/f1/f2).
template<int CONV, int ACT, int RESID, int OUTBF>
__global__ __launch_bounds__(256)
void gemm_k(const ushort* __restrict__ A, const ushort* __restrict__ B,
            const float* __restrict__ bias, const ushort* __restrict__ R,
            void* __restrict__ Cout, int M, int N, int K,
            const ushort* __restrict__ Xp) {
    __shared__ __align__(16) ushort As[128 * 32];
    __shared__ __align__(16) ushort Bs[128 * 32];
    const int tid  = threadIdx.x;
    const int lane = tid & 63, wave = tid >> 6;
    const int wr = wave >> 1, wc = wave & 1;
    const int lm = lane & 15, quad = lane >> 4;

    const int NP = gridDim.x, My = gridDim.y;
    int m_idx, n_idx;
    if ((My & 7) == 0) {
        int bid = blockIdx.y * NP + blockIdx.x;
        m_idx = (bid & 7) + 8 * (bid / (8 * NP));
        n_idx = (bid >> 3) % NP;
    } else {
        m_idx = blockIdx.y; n_idx = blockIdx.x;
    }
    const int m0 = m_idx * 128, n0 = n_idx * 128;

    const int srow   = lane >> 2;        // 0..15
    const int schunk = (lane & 3) * 8;   // k offset (elems)
    ushort* AsW = As + wave * 32 * 32;
    ushort* BsW = Bs + wave * 32 * 32;

    f32x4 acc[4][4];
#pragma unroll
    for (int mt = 0; mt < 4; mt++)
#pragma unroll
        for (int nt = 0; nt < 4; nt++) acc[mt][nt] = (f32x4){0.f, 0.f, 0.f, 0.f};

    for (int k0 = 0; k0 < K; k0 += 32) {
        if (CONV) {
            int dt = k0 >> 10;
            int ci = (k0 & 1023) + schunk;
            int g0 = m0 + wave * 32 + srow;
            int bn0 = g0 >> 8, t0 = g0 & 255;
            int g1 = g0 + 16;
            int bn1 = g1 >> 8, t1 = g1 & 255;
            gl2lds(Xp + (size_t)bn0 * XROW + (t0 + dt) * 1024 + ci, AsW);
            gl2lds(Xp + (size_t)bn1 * XROW + (t1 + dt) * 1024 + ci, AsW + 16 * 32);
        } else {
            const ushort* ga = A + (size_t)(m0 + wave * 32 + srow) * K + k0 + schunk;
            gl2lds(ga, AsW);
            gl2lds(ga + (size_t)16 * K, AsW + 16 * 32);
        }
        {
            const ushort* gb = B + (size_t)(n0 + wave * 32 + srow) * K + k0 + schunk;
            gl2lds(gb, BsW);
            gl2lds(gb + (size_t)16 * K, BsW + 16 * 32);
        }
        __syncthreads();
        short8 af[4], bfv[4];
#pragma unroll
        for (int mt = 0; mt < 4; mt++)
            af[mt] = *(const short8*)&As[(wr * 64 + mt * 16 + lm) * 32 + quad * 8];
#pragma unroll
        for (int nt = 0; nt < 4; nt++)
            bfv[nt] = *(const short8*)&Bs[(wc * 64 + nt * 16 + lm) * 32 + quad * 8];
#pragma unroll
        for (int mt = 0; mt < 4; mt++)
#pragma unroll
            for (int nt = 0; nt < 4; nt++)
                acc[mt][nt] = __builtin_amdgcn_mfma_f32_16x16x32_bf16(
                    af[mt], bfv[nt], acc[mt][nt], 0, 0, 0);
        __syncthreads();
    }

#pragma unroll
    for (int mt = 0; mt < 4; mt++) {
        int grow0 = m0 + wr * 64 + mt * 16 + quad * 4;
#pragma unroll
        for (int nt = 0; nt < 4; nt++) {
            int gcol = n0 + wc * 64 + nt * 16 + lm;
            float bia = bias ? bias[gcol] : 0.0f;
            f32x4 v = acc[mt][nt];
#pragma unroll
            for (int i = 0; i < 4; i++) {
                int grow = grow0 + i;
                float val = v[i] + bia;
                if (ACT == 1) val = val * 0.5f * (1.0f + erff(val * 0.70710678118654752f));
                if (ACT == 2) val = fmaxf(val, 0.0f);
                if (RESID) val += b2f(R[(size_t)grow * N + gcol]);
                if (OUTBF) ((ushort*)Cout)[(size_t)grow * N + gcol] = f2b(val);
                else       ((float*)Cout)[(size_t)grow * N + gcol]  = val;
            }
        }
    }
}

// ================= flash-style softmax attention (o1 half), MFMA ============
__global__ __launch_bounds__(256)
void attn1_k(const ushort* __restrict__ qkvt, ushort* __restrict__ O) {
    const int bn = blockIdx.x, h = blockIdx.y;
    const int tid = threadIdx.x;
    const int wave = tid >> 6, lane = tid & 63;
    const int lm = lane & 15, quad = lane >> 4;
    __shared__ __align__(16) ushort Ks[32 * 136];
    __shared__ __align__(16) ushort Vt[128 * 40];
    __shared__ __align__(16) ushort Ps[4][64 * 40];
    const ushort* base = qkvt + (size_t)bn * T_ * 2048;

    short8 aq[4][4];
#pragma unroll
    for (int mt = 0; mt < 4; mt++) {
        const ushort* qrow = base + (size_t)(wave * 64 + mt * 16 + lm) * 2048 + h * DH_;
#pragma unroll
        for (int ks = 0; ks < 4; ks++)
            aq[mt][ks] = *(const short8*)(qrow + ks * 32 + quad * 8);
    }

    f32x4 oacc[4][8];
#pragma unroll
    for (int mt = 0; mt < 4; mt++)
#pragma unroll
        for (int nt = 0; nt < 8; nt++) oacc[mt][nt] = (f32x4){0.f, 0.f, 0.f, 0.f};
    float mrow[4][4], lrow[4][4];
#pragma unroll
    for (int mt = 0; mt < 4; mt++)
#pragma unroll
        for (int i = 0; i < 4; i++) { mrow[mt][i] = -1e30f; lrow[mt][i] = 0.0f; }

    for (int kt = 0; kt < 8; kt++) {
        __syncthreads();
#pragma unroll
        for (int u = 0; u < 2; u++) {
            int ii = tid + u * 256;
            int j = ii >> 4, dc = ii & 15;
            *(uint4*)&Ks[j * 136 + dc * 8] =
                *(const uint4*)(base + (size_t)(kt * 32 + j) * 2048 + 512 + h * DH_ + dc * 8);
        }
        {
            int j = tid & 31, half = tid >> 5;
            const ushort* vrow = base + (size_t)(kt * 32 + j) * 2048 + 1024 + h * DH_ + half * 16;
            uint4 v0 = *(const uint4*)vrow;
            uint4 v1 = *(const uint4*)(vrow + 8);
            ushort e[16];
            *(uint4*)&e[0] = v0; *(uint4*)&e[8] = v1;
#pragma unroll
            for (int u = 0; u < 16; u++)
                Vt[(half * 16 + u) * 40 + j] = e[u];
        }
        __syncthreads();

        f32x4 s[4][2];
#pragma unroll
        for (int mt = 0; mt < 4; mt++)
#pragma unroll
            for (int nt = 0; nt < 2; nt++) s[mt][nt] = (f32x4){0.f, 0.f, 0.f, 0.f};
#pragma unroll
        for (int ks = 0; ks < 4; ks++) {
            short8 bk0 = *(const short8*)&Ks[lm * 136 + ks * 32 + quad * 8];
            short8 bk1 = *(const short8*)&Ks[(16 + lm) * 136 + ks * 32 + quad * 8];
#pragma unroll
            for (int mt = 0; mt < 4; mt++) {
                s[mt][0] = __builtin_amdgcn_mfma_f32_16x16x32_bf16(aq[mt][ks], bk0, s[mt][0], 0, 0, 0);
                s[mt][1] = __builtin_amdgcn_mfma_f32_16x16x32_bf16(aq[mt][ks], bk1, s[mt][1], 0, 0, 0);
            }
        }

#pragma unroll
        for (int mt = 0; mt < 4; mt++) {
#pragma unroll
            for (int i = 0; i < 4; i++) {
                float v0 = s[mt][0][i] * SCALE_;
                float v1 = s[mt][1][i] * SCALE_;
                float rmax = fmaxf(v0, v1);
#pragma unroll
                for (int mk = 1; mk < 16; mk <<= 1)
                    rmax = fmaxf(rmax, __shfl_xor(rmax, mk));
                float mold = mrow[mt][i];
                float mnew = fmaxf(mold, rmax);
                float alpha = __expf(mold - mnew);
                float p0 = __expf(v0 - mnew);
                float p1 = __expf(v1 - mnew);
                float rs = p0 + p1;
#pragma unroll
                for (int mk = 1; mk < 16; mk <<= 1)
                    rs += __shfl_xor(rs, mk);
                lrow[mt][i] = lrow[mt][i] * alpha + rs;
                mrow[mt][i] = mnew;
#pragma unroll
                for (int nt = 0; nt < 8; nt++) {
                    oacc[mt][nt][i] *= alpha;
                }
                int prow = mt * 16 + quad * 4 + i;
                Ps[wave][prow * 40 + lm]      = f2b(p0);
                Ps[wave][prow * 40 + 16 + lm] = f2b(p1);
            }
        }

        short8 ap[4];
#pragma unroll
        for (int mt = 0; mt < 4; mt++)
            ap[mt] = *(const short8*)&Ps[wave][(mt * 16 + lm) * 40 + quad * 8];
#pragma unroll
        for (int nt = 0; nt < 8; nt++) {
            short8 bv = *(const short8*)&Vt[(nt * 16 + lm) * 40 + quad * 8];
#pragma unroll
            for (int mt = 0; mt < 4; mt++)
                oacc[mt][nt] = __builtin_amdgcn_mfma_f32_16x16x32_bf16(ap[mt], bv, oacc[mt][nt], 0, 0, 0);
        }
    }

#pragma unroll
    for (int mt = 0; mt < 4; mt++) {
#pragma unroll
        for (int i = 0; i < 4; i++) {
            int row = wave * 64 + mt * 16 + quad * 4 + i;
            float rinv = 1.0f / lrow[mt][i];
#pragma unroll
            for (int nt = 0; nt < 8; nt++) {
                int d = nt * 16 + lm;
                O[((size_t)bn * T_ + row) * 1024 + h * 256 + d] =
                    f2b(oacc[mt][nt][i] * rinv);
            }
        }
    }
}

// ================= decay attention (o2 half): o2 = A2 @ T, batched over bn ==
__global__ __launch_bounds__(256)
void attn2_k(const ushort* __restrict__ A2, const ushort* __restrict__ qkvt,
             ushort* __restrict__ O) {
    __shared__ __align__(16) ushort As[128 * LDT];
    __shared__ __align__(16) ushort Bs[128 * 48];
    const int tid = threadIdx.x;
    const int bn = blockIdx.z;
    const int m0 = blockIdx.y * 128;
    const int n0 = blockIdx.x * 128;
    const int lane = tid & 63, wave = tid >> 6;
    const int wr = wave >> 1, wc = wave & 1;
    const int lm = lane & 15, quad = lane >> 4;
    const ushort* tbase = qkvt + (size_t)bn * T_ * 2048 + 1536;
    const int r = tid >> 1, c0 = (tid & 1) * 2;

    f32x4 acc[4][4];
#pragma unroll
    for (int mt = 0; mt < 4; mt++)
#pragma unroll
        for (int nt = 0; nt < 4; nt++) acc[mt][nt] = (f32x4){0.f, 0.f, 0.f, 0.f};

    for (int k0 = 0; k0 < 256; k0 += 32) {
        const ushort* Arow = A2 + (size_t)(m0 + r) * 256 + k0;
        *(uint4*)&As[r * LDT + c0 * 8]       = *(const uint4*)(Arow + c0 * 8);
        *(uint4*)&As[r * LDT + (c0 + 1) * 8] = *(const uint4*)(Arow + (c0 + 1) * 8);
        {
            int kr = tid & 31, np = tid >> 5;
            const ushort* trow = tbase + (size_t)(k0 + kr) * 2048 + n0 + np * 16;
            uint4 v0 = *(const uint4*)trow;
            uint4 v1 = *(const uint4*)(trow + 8);
            ushort e[16];
            *(uint4*)&e[0] = v0; *(uint4*)&e[8] = v1;
#pragma unroll
            for (int u = 0; u < 16; u++)
                Bs[(np * 16 + u) * 48 + kr] = e[u];
        }
        __syncthreads();
        short8 af[4], bf[4];
#pragma unroll
        for (int mt = 0; mt < 4; mt++)
            af[mt] = *(const short8*)&As[(wr * 64 + mt * 16 + lm) * LDT + quad * 8];
#pragma unroll
        for (int nt = 0; nt < 4; nt++)
            bf[nt] = *(const short8*)&Bs[(wc * 64 + nt * 16 + lm) * 48 + quad * 8];
#pragma unroll
        for (int mt = 0; mt < 4; mt++)
#pragma unroll
            for (int nt = 0; nt < 4; nt++)
                acc[mt][nt] = __builtin_amdgcn_mfma_f32_16x16x32_bf16(
                    af[mt], bf[nt], acc[mt][nt], 0, 0, 0);
        __syncthreads();
    }

#pragma unroll
    for (int mt = 0; mt < 4; mt++) {
        int row0 = m0 + wr * 64 + mt * 16 + quad * 4;
#pragma unroll
        for (int nt = 0; nt < 4; nt++) {
            int n = n0 + wc * 64 + nt * 16 + lm;
            int h = n >> 7, d = n & 127;
#pragma unroll
            for (int i = 0; i < 4; i++) {
                int row = row0 + i;
                O[((size_t)bn * T_ + row) * 1024 + h * 256 + 128 + d] =
                    f2b(acc[mt][nt][i]);
            }
        }
    }
}

// ============ head stage 1: x1 = h @ c1W^T + c1b  (M x 32, K=512, MFMA) =====
#define BLD 520
__global__ __launch_bounds__(256)
void head1_k(const ushort* __restrict__ Hb, const ushort* __restrict__ c1Wb,
             const float* __restrict__ c1b, float* __restrict__ X1) {
    __shared__ __align__(16) ushort As[128 * LDT];
    __shared__ __align__(16) ushort Bs[32 * BLD];
    const int tid = threadIdx.x;
    const int lane = tid & 63, wave = tid >> 6;
    const int lm = lane & 15, quad = lane >> 4;
    const int m0 = blockIdx.x * 128;
#pragma unroll
    for (int u = 0; u < 8; u++) {
        int ii = tid + u * 256;
        int nrow = ii >> 6;
        int koff = (ii & 63) * 8;
        *(uint4*)&Bs[nrow * BLD + koff] = *(const uint4*)(c1Wb + nrow * 512 + koff);
    }
    f32x4 acc[2][2];
#pragma unroll
    for (int mt = 0; mt < 2; mt++)
#pragma unroll
        for (int nt = 0; nt < 2; nt++) acc[mt][nt] = (f32x4){0.f, 0.f, 0.f, 0.f};

    const int r = tid >> 1, half = tid & 1;
    for (int k0 = 0; k0 < 512; k0 += 32) {
        const ushort* s = Hb + (size_t)(m0 + r) * 512 + k0 + half * 16;
        uint4 v0 = *(const uint4*)s;
        uint4 v1 = *(const uint4*)(s + 8);
        __syncthreads();
        *(uint4*)&As[r * LDT + half * 16]     = v0;
        *(uint4*)&As[r * LDT + half * 16 + 8] = v1;
        __syncthreads();
        short8 af[2], bf[2];
#pragma unroll
        for (int mt = 0; mt < 2; mt++)
            af[mt] = *(const short8*)&As[(wave * 32 + mt * 16 + lm) * LDT + quad * 8];
#pragma unroll
        for (int nt = 0; nt < 2; nt++)
            bf[nt] = *(const short8*)&Bs[(nt * 16 + lm) * BLD + k0 + quad * 8];
#pragma unroll
        for (int mt = 0; mt < 2; mt++)
#pragma unroll
            for (int nt = 0; nt < 2; nt++)
                acc[mt][nt] = __builtin_amdgcn_mfma_f32_16x16x32_bf16(
                    af[mt], bf[nt], acc[mt][nt], 0, 0, 0);
    }
#pragma unroll
    for (int mt = 0; mt < 2; mt++) {
        int row0 = m0 + wave * 32 + mt * 16 + quad * 4;
#pragma unroll
        for (int nt = 0; nt < 2; nt++) {
            int col = nt * 16 + lm;
            float bia = c1b[col];
#pragma unroll
            for (int i = 0; i < 4; i++)
                X1[(size_t)(row0 + i) * 32 + col] = acc[mt][nt][i] + bia;
        }
    }
}

// ============ head stage 2: one thread per (bn,t) row ========================
__global__ __launch_bounds__(256)
void head2_k(const float* __restrict__ X1, int bn_base, int M,
             const float* __restrict__ g1, const float* __restrict__ b1,
             const float* __restrict__ m1, const float* __restrict__ v1,
             const float* __restrict__ c2W, const float* __restrict__ c2b,
             const float* __restrict__ g2, const float* __restrict__ b2,
             const float* __restrict__ m2, const float* __restrict__ v2,
             const float* __restrict__ c3W, const float* __restrict__ c3b,
             float* __restrict__ sum_dist, float* __restrict__ sum_score) {
    int row = blockIdx.x * 256 + threadIdx.x;
    if (row >= M) return;
    float x1[32], y1[32];
    const float* xr = X1 + (size_t)row * 32;
#pragma unroll
    for (int c = 0; c < 32; c++) x1[c] = xr[c];
    float d1 = 0.0f;
#pragma unroll
    for (int c = 0; c < 32; c++) {
        float dd = x1[c] - m1[c];
        d1 += dd * dd / v1[c];
        y1[c] = fmaxf(0.0f, dd * rsqrtf(v1[c] + LEPS) * g1[c] + b1[c]);
    }
    float d2 = 0.0f, sc = c3b[0];
#pragma unroll
    for (int o = 0; o < 16; o++) {
        float acc = c2b[o];
        const float* wr = c2W + o * 32;
#pragma unroll
        for (int c = 0; c < 32; c++) acc += wr[c] * y1[c];
        float dd = acc - m2[o];
        d2 += dd * dd / v2[o];
        float y2 = fmaxf(0.0f, dd * rsqrtf(v2[o] + LEPS) * g2[o] + b2[o]);
        sc += c3W[o] * y2;
    }
    float dist = sqrtf(d1) + sqrtf(d2);
    sc = 1.0f / (1.0f + expf(-sc));
    int bn = bn_base + (row >> 8);
    int t = row & 255;
    int b = bn / 10;
    atomicAdd(&sum_dist[b * T_ + t], dist);
    atomicAdd(&sum_score[b * T_ + t], sc);
}

// --------------------------------------------------------------- final out
__global__ void combine_k(const float* __restrict__ sd, const float* __restrict__ ss,
                          float* __restrict__ out) {
    int i = blockIdx.x * 256 + threadIdx.x;
    if (i < 16 * T_) out[i] = (sd[i] * 0.1f) * (ss[i] * 0.1f);
}

// ===========================================================================
extern "C" void kernel_launch(void* const* d_in, const int* in_sizes, int n_in,
                              void* d_out, int out_size, void* d_ws, size_t ws_size,
                              hipStream_t stream) {
    const float* x     = (const float*)d_in[0];
    const float* W_emb = (const float*)d_in[1];
    const float* b_emb = (const float*)d_in[2];
    const float* ln1_g = (const float*)d_in[3];
    const float* ln1_b = (const float*)d_in[4];
    const float* W_qkv = (const float*)d_in[5];
    const float* W_o   = (const float*)d_in[6];
    const float* b_o   = (const float*)d_in[7];
    const float* ln2_g = (const float*)d_in[8];
    const float* ln2_b = (const float*)d_in[9];
    const float* W_f1  = (const float*)d_in[10];
    const float* b_f1  = (const float*)d_in[11];
    const float* W_f2  = (const float*)d_in[12];
    const float* b_f2  = (const float*)d_in[13];
    const float* c1_W  = (const float*)d_in[14];
    const float* c1_b  = (const float*)d_in[15];
    const float* bn1_g = (const float*)d_in[16];
    const float* bn1_b = (const float*)d_in[17];
    const float* bn1_m = (const float*)d_in[18];
    const float* bn1_v = (const float*)d_in[19];
    const float* c2_W  = (const float*)d_in[20];
    const float* c2_b  = (const float*)d_in[21];
    const float* bn2_g = (const float*)d_in[22];
    const float* bn2_b = (const float*)d_in[23];
    const float* bn2_m = (const float*)d_in[24];
    const float* bn2_v = (const float*)d_in[25];
    const float* c3_W  = (const float*)d_in[26];
    const float* c3_b  = (const float*)d_in[27];
    float* out = (float*)d_out;

    // ---------------- workspace layout (runtime-chunked over bn) ----------
    char* p = (char*)d_ws;
    auto alloc = [&](size_t bytes) -> char* {
        char* q = p; p += (bytes + 255) & ~(size_t)255; return q;
    };
    ushort* wEmb = (ushort*)alloc((size_t)C_ * 3072 * 2);
    ushort* wQkv = (ushort*)alloc((size_t)2 * 2048 * 512 * 2);
    ushort* wO   = (ushort*)alloc((size_t)2 * 512 * 1024 * 2);
    ushort* wF1  = (ushort*)alloc((size_t)2 * 512 * 512 * 2);
    ushort* wF2  = (ushort*)alloc((size_t)2 * 512 * 512 * 2);
    ushort* A2bf = (ushort*)alloc((size_t)256 * 256 * 2);
    ushort* c1Wb = (ushort*)alloc((size_t)32 * 512 * 2);
    float*  s256      = (float*)alloc(256 * 4);
    float*  sum_dist  = (float*)alloc(4096 * 4);
    float*  sum_score = (float*)alloc(4096 * 4);
    size_t fixedB = (size_t)(p - (char*)d_ws);

    // per-row bytes: xbp 2064 + h 1024 + z 1024 + qkvt 4096 + o 2048 + X1 128 = 10384
    int CH = 8;
    const int cands[7] = {160, 80, 40, 32, 20, 16, 10};
    for (int ci = 0; ci < 7; ci++) {
        size_t per = (size_t)cands[ci] * 256 * 10384 + 16384;
        if (fixedB + per <= ws_size) { CH = cands[ci]; break; }
    }
    const int MR = CH * 256;
    ushort* xbp  = (ushort*)alloc((size_t)CH * XROW * 2);
    ushort* h    = (ushort*)alloc((size_t)MR * 512 * 2);
    ushort* z    = (ushort*)alloc((size_t)MR * 512 * 2);
    ushort* qkvt = (ushort*)alloc((size_t)MR * 2048 * 2);
    ushort* o    = (ushort*)alloc((size_t)MR * 1024 * 2);
    ushort* g    = o;
    float*  X1   = (float*)alloc((size_t)MR * 32 * 4);

    // ---------------- once-per-launch prep ----------------
    zero_k<<<(8192 + 255) / 256, 256, 0, stream>>>(sum_dist, 8192);
    a2_colsum_k<<<1, 256, 0, stream>>>(s256);
    a2fill_k<<<256, 256, 0, stream>>>(s256, A2bf);
    wemb_k<<<(C_ * 3072 + 255) / 256, 256, 0, stream>>>(W_emb, wEmb);
    bcvt_k<<<(32 * 512 + 255) / 256, 256, 0, stream>>>(c1_W, c1Wb, 32 * 512);
    for (int l = 0; l < 2; l++) {
        tconv_k<<<dim3(512 / 32, 2048 / 32), 256, 0, stream>>>(
            W_qkv + (size_t)l * 512 * 2048, wQkv + (size_t)l * 2048 * 512, 512, 2048);
        tconv_k<<<dim3(1024 / 32, 512 / 32), 256, 0, stream>>>(
            W_o + (size_t)l * 1024 * 512, wO + (size_t)l * 512 * 1024, 1024, 512);
        tconv_k<<<dim3(512 / 32, 512 / 32), 256, 0, stream>>>(
            W_f1 + (size_t)l * 512 * 512, wF1 + (size_t)l * 512 * 512, 512, 512);
        tconv_k<<<dim3(512 / 32, 512 / 32), 256, 0, stream>>>(
            W_f2 + (size_t)l * 512 * 512, wF2 + (size_t)l * 512 * 512, 512, 512);
    }

    // ---------------- pipeline, chunked over bn ----------------
    for (int cs = 0; cs < BNB; cs += CH) {
        const float* xc = x + (size_t)cs * T_ * D_;

        // x chunk -> bf16 padded + zero pad rows
        int n4 = MR * 1024 / 4;
        xcvt_k<<<(n4 + 255) / 256, 256, 0, stream>>>(xc, xbp, n4);
        xpad_k<<<(CH * 1024 + 255) / 256, 256, 0, stream>>>(xbp, CH);

        // conv1d(k=3,pad=1)+ReLU as implicit-im2row MFMA GEMM -> h bf16
        gemm256_k<1, 2, 0, 1><<<dim3(512 / 256, MR / 256), 512, 0, stream>>>(
            nullptr, wEmb, b_emb, nullptr, h, MR, 512, 3072, xbp);

        for (int l = 0; l < 2; l++) {
            ln_k<<<MR / 4, 256, 0, stream>>>(h, ln1_g + l * C_, ln1_b + l * C_, z);
            gemm256_k<0, 0, 0, 1><<<dim3(2048 / 256, MR / 256), 512, 0, stream>>>(
                z, wQkv + (size_t)l * 2048 * 512, nullptr, nullptr, qkvt,
                MR, 2048, 512, nullptr);
            attn1_k<<<dim3(CH, H_), 256, 0, stream>>>(qkvt, o);
            attn2_k<<<dim3(4, 2, CH), 256, 0, stream>>>(A2bf, qkvt, o);
            gemm_k<0, 0, 1, 1><<<dim3(512 / 128, MR / 128), 256, 0, stream>>>(
                o, wO + (size_t)l * 512 * 1024, b_o + l * C_, h, h,
                MR, 512, 1024, nullptr);
            ln_k<<<MR / 4, 256, 0, stream>>>(h, ln2_g + l * C_, ln2_b + l * C_, z);
            gemm_k<0, 1, 0, 1><<<dim3(512 / 128, MR / 128), 256, 0, stream>>>(
                z, wF1 + (size_t)l * 512 * 512, b_f1 + l * C_, nullptr, g,
                MR, 512, 512, nullptr);
            gemm_k<0, 0, 1, 1><<<dim3(512 / 128, MR / 128), 256, 0, stream>>>(
                g, wF2 + (size_t)l * 512 * 512, b_f2 + l * C_, h, h,
                MR, 512, 512, nullptr);
        }

        head1_k<<<MR / 128, 256, 0, stream>>>(h, c1Wb, c1_b, X1);
        head2_k<<<MR / 256, 256, 0, stream>>>(
            X1, cs, MR, bn1_g, bn1_b, bn1_m, bn1_v,
            c2_W, c2_b, bn2_g, bn2_b, bn2_m, bn2_v, c3_W, c3_b,
            sum_dist, sum_score);
    }

    combine_k<<<16, 256, 0, stream>>>(sum_dist, sum_score, out);
}